// Round 12
// baseline (445.857 us; speedup 1.0000x reference)
//
#include <hip/hip_runtime.h>
#include <cfloat>

// Problem constants (match reference)
constexpr int Bn = 1024, Ln = 1024, Vn = 20, Dn = 128;
constexpr int NJ = 2 * Vn;      // 40 output columns
constexpr int TB = 32;          // steps per resync block
constexpr int CH = 2;           // chains per wave (lanes 0-31 / 32-63)

// v mod 20 for 0 <= v <= ~4000 (magic multiply, exact in this range)
__device__ __forceinline__ int mod20(int v) { return v - 20 * ((v * 205) >> 12); }

// ---- DPP helpers: in-row (16-lane) butterfly max, pure VALU (proven R7) ----
template<int CTRL>
__device__ __forceinline__ float dpp_max(float v) {
  const int s = __builtin_amdgcn_update_dpp(0, __float_as_int(v), CTRL, 0xF, 0xF, false);
  return fmaxf(v, __int_as_float(s));
}
__device__ __forceinline__ float rowmax16(float v) {
  v = dpp_max<0xB1>(v);    // quad_perm xor1
  v = dpp_max<0x4E>(v);    // quad_perm xor2
  v = dpp_max<0x141>(v);   // row_half_mirror
  v = dpp_max<0x140>(v);   // row_mirror
  return v;
}

// inv mod 20 packed table: 5-bit entries for odd s, indexed by s>>1
constexpr unsigned long long INVT =
    (1ull << 0) | (7ull << 5) | (0ull << 10) | (3ull << 15) | (9ull << 20) |
    (11ull << 25) | (17ull << 30) | (0ull << 35) | (13ull << 40) | (19ull << 45);

// ---- 128 named f64 W-column registers (same codegen as R11) ----
#define WD(d) double wd##d = (double)Ws[(d)*NJ + jc]; \
  asm volatile("" : "+v"(wd##d));
#define WD8(a,b,c,d_,e,f,g,h) WD(a) WD(b) WD(c) WD(d_) WD(e) WD(f) WD(g) WD(h)

// resync dot step: 4 dims, 2 uniform b128 reads, 4 acc chains
#define R4(i0,i1,i2,i3) { \
  const double2 sA_ = st2[(i0) >> 1]; \
  const double2 sB_ = st2[(i2) >> 1]; \
  a0 = __builtin_fma(sA_.x, wd##i0, a0); \
  a1 = __builtin_fma(sA_.y, wd##i1, a1); \
  a2 = __builtin_fma(sB_.x, wd##i2, a2); \
  a3 = __builtin_fma(sB_.y, wd##i3, a3); }
#define RDOT \
  R4(0,1,2,3)       R4(4,5,6,7)       R4(8,9,10,11)     R4(12,13,14,15)   \
  R4(16,17,18,19)   R4(20,21,22,23)   R4(24,25,26,27)   R4(28,29,30,31)   \
  R4(32,33,34,35)   R4(36,37,38,39)   R4(40,41,42,43)   R4(44,45,46,47)   \
  R4(48,49,50,51)   R4(52,53,54,55)   R4(56,57,58,59)   R4(60,61,62,63)   \
  R4(64,65,66,67)   R4(68,69,70,71)   R4(72,73,74,75)   R4(76,77,78,79)   \
  R4(80,81,82,83)   R4(84,85,86,87)   R4(88,89,90,91)   R4(92,93,94,95)   \
  R4(96,97,98,99)   R4(100,101,102,103) R4(104,105,106,107) R4(108,109,110,111) \
  R4(112,113,114,115) R4(116,117,118,119) R4(120,121,122,123) R4(124,125,126,127)

__global__ __launch_bounds__(64, 1) void daf_chain(
    const float* __restrict__ x, const float* __restrict__ emb,
    const float* __restrict__ W, const float* __restrict__ bvec,
    float* __restrict__ out)
{
  __shared__ float Ws[Dn * NJ];                  // 20480 B: W row-major f32
  __shared__ float embd[Vn * Dn];                // 10240 B: emb rows f32
  __shared__ alignas(8) float ewd2[Vn * 64];     //  5120 B: EW distributed {lo,hi}/pos
  __shared__ alignas(16) double st64[Dn];        //  1024 B: f64 state (per pass)
  __shared__ float nets40[64];                   //   256 B: resync share (padded)
  __shared__ alignas(16) unsigned char aidxA[Ln]; // 1024 B: chain A tokens
  __shared__ alignas(16) unsigned char aidxB[Ln]; // 1024 B: chain B tokens

  const int lane = threadIdx.x;
  const int batchA = blockIdx.x * CH;
  const int batchB = batchA + 1;
  const int p   = lane & 15;          // position within 16-lane row
  const int rB  = (lane >> 4) & 1;    // 0 = loc row, 1 = scale row (per chain)
  const int pos = lane & 31;          // position within chain half
  const bool isB = lane >= 32;        // chain select

  // resync column ownership (40 owner lanes; wave-wide per pass)
  const bool own = (lane < Vn) || (lane >= 32 && lane < 32 + Vn);
  const int  jm  = (lane < 32) ? lane : (lane - 32 + Vn);
  const int  jc  = own ? jm : 0;

  // ---- Prologue: stage W, emb; extract both chains' tokens ----
  for (int i = lane; i < Dn * NJ; i += 64) Ws[i] = W[i];
  for (int i = lane; i < Vn * Dn; i += 64) embd[i] = emb[i];
  {
    const float4* xa4 = (const float4*)(x + (size_t)batchA * Ln * Vn);
    const float4* xb4 = (const float4*)(x + (size_t)batchB * Ln * Vn);
    for (int i = lane; i < Ln * (Vn / 4); i += 64) {
      const int row = i / 5, cb = (i % 5) * 4;
      const float4 va = xa4[i];
      if (va.x > 0.5f) aidxA[row] = (unsigned char)(cb + 0);
      if (va.y > 0.5f) aidxA[row] = (unsigned char)(cb + 1);
      if (va.z > 0.5f) aidxA[row] = (unsigned char)(cb + 2);
      if (va.w > 0.5f) aidxA[row] = (unsigned char)(cb + 3);
      const float4 vb = xb4[i];
      if (vb.x > 0.5f) aidxB[row] = (unsigned char)(cb + 0);
      if (vb.y > 0.5f) aidxB[row] = (unsigned char)(cb + 1);
      if (vb.z > 0.5f) aidxB[row] = (unsigned char)(cb + 2);
      if (vb.w > 0.5f) aidxB[row] = (unsigned char)(cb + 3);
    }
  }

  // ---- EW[k][j] = f64 dot(emb[k], W[:,j]) -> f32, distributed layout (R7) ----
  for (int e = lane; e < Vn * NJ; e += 64) {
    const int k = e / NJ, j = e - k * NJ;
    double acc = 0.0;
#pragma unroll 4
    for (int d = 0; d < Dn; ++d)
      acc = __builtin_fma((double)embd[k * Dn + d], (double)Ws[d * NJ + j], acc);
    int q, slot;
    if (j < 16)      { q = j;             slot = 0; }
    else if (j < 20) { q = j - 16;        slot = 1; }
    else if (j < 36) { q = 16 + (j - 20); slot = 0; }
    else             { q = 16 + (j - 36); slot = 1; }
    ewd2[k * 64 + q * 2 + slot] = (float)acc;
  }
  if ((pos & 15) >= 4)   // zero undefined hi slots so (-FLT_MAX += 0) stays put
    for (int k = 0; k < Vn; ++k) ewd2[k * 64 + pos * 2 + 1] = 0.0f;

  // ---- W column (per-lane col jc) f64 (same as R11) ----
  WD8(0,1,2,3,4,5,6,7)          WD8(8,9,10,11,12,13,14,15)
  WD8(16,17,18,19,20,21,22,23)  WD8(24,25,26,27,28,29,30,31)
  WD8(32,33,34,35,36,37,38,39)  WD8(40,41,42,43,44,45,46,47)
  WD8(48,49,50,51,52,53,54,55)  WD8(56,57,58,59,60,61,62,63)
  WD8(64,65,66,67,68,69,70,71)  WD8(72,73,74,75,76,77,78,79)
  WD8(80,81,82,83,84,85,86,87)  WD8(88,89,90,91,92,93,94,95)
  WD8(96,97,98,99,100,101,102,103)     WD8(104,105,106,107,108,109,110,111)
  WD8(112,113,114,115,116,117,118,119) WD8(120,121,122,123,124,125,126,127)

  // ---- init nets (distributed, per chain): exact f32 b (state 0) ----
  const int jlo = rB ? (20 + p) : p;
  float nlo = bvec[jlo];
  float nhi = (p < 4) ? bvec[jlo + 16] : -FLT_MAX;
  const double bj = (double)bvec[jc];

  // per-chain f32 state walk regs: this lane holds dims {pos, pos+64} of BOTH chains
  float sAa = 0.0f, sAb = 0.0f, sBa = 0.0f, sBb = 0.0f;
  float* outA = out + (size_t)batchA * Ln * Vn;
  float* outB = out + (size_t)batchB * Ln * Vn;
  const double2* st2 = (const double2*)st64;
  const float2*  ew2 = (const float2*)ewd2;

  for (int tb = 0; tb < Ln / TB; ++tb) {
    // token prefetch: 32 tokens per chain -> 16 SGPRs
    const uint4 ta0 = *(const uint4*)(aidxA + tb * TB);
    const uint4 ta1 = *(const uint4*)(aidxA + tb * TB + 16);
    const uint4 tb0 = *(const uint4*)(aidxB + tb * TB);
    const uint4 tb1 = *(const uint4*)(aidxB + tb * TB + 16);
    const int kA0 = __builtin_amdgcn_readfirstlane((int)ta0.x);
    const int kA1 = __builtin_amdgcn_readfirstlane((int)ta0.y);
    const int kA2 = __builtin_amdgcn_readfirstlane((int)ta0.z);
    const int kA3 = __builtin_amdgcn_readfirstlane((int)ta0.w);
    const int kA4 = __builtin_amdgcn_readfirstlane((int)ta1.x);
    const int kA5 = __builtin_amdgcn_readfirstlane((int)ta1.y);
    const int kA6 = __builtin_amdgcn_readfirstlane((int)ta1.z);
    const int kA7 = __builtin_amdgcn_readfirstlane((int)ta1.w);
    const int kB0 = __builtin_amdgcn_readfirstlane((int)tb0.x);
    const int kB1 = __builtin_amdgcn_readfirstlane((int)tb0.y);
    const int kB2 = __builtin_amdgcn_readfirstlane((int)tb0.z);
    const int kB3 = __builtin_amdgcn_readfirstlane((int)tb0.w);
    const int kB4 = __builtin_amdgcn_readfirstlane((int)tb1.x);
    const int kB5 = __builtin_amdgcn_readfirstlane((int)tb1.y);
    const int kB6 = __builtin_amdgcn_readfirstlane((int)tb1.z);
    const int kB7 = __builtin_amdgcn_readfirstlane((int)tb1.w);

    unsigned long long qA0 = 0ull, qA1 = 0ull, qA2 = 0ull;  // 32 x 5-bit oidx A
    unsigned long long qB0 = 0ull, qB1 = 0ull, qB2 = 0ull;  // 32 x 5-bit oidx B

#pragma unroll
    for (int u = 0; u < TB; ++u) {
      const int twA = (u < 4) ? kA0 : (u < 8) ? kA1 : (u < 12) ? kA2 :
                      (u < 16) ? kA3 : (u < 20) ? kA4 : (u < 24) ? kA5 :
                      (u < 28) ? kA6 : kA7;
      const int twB = (u < 4) ? kB0 : (u < 8) ? kB1 : (u < 12) ? kB2 :
                      (u < 16) ? kB3 : (u < 20) ? kB4 : (u < 24) ? kB5 :
                      (u < 28) ? kB6 : kB7;
      const int asA = (twA >> ((u & 3) * 8)) & 0xFF;   // SALU extract
      const int asB = (twB >> ((u & 3) * 8)) & 0xFF;

      // ---- shared argmax machinery: one rowmax16 + two ballots serve BOTH
      //      chains (DPP rows of 16 reduce each group independently) ----
      float m = fmaxf(nlo, nhi);
      m = rowmax16(m);
      const unsigned long long bLo = __ballot(nlo == m);
      const unsigned long long bHi = __ballot(nhi == m);
      // chain A (bits 0-31), chain B (bits 32-63)
      const unsigned wLocA = ((unsigned)bLo & 0xFFFFu) | (((unsigned)bHi & 0xFu) << 16);
      const unsigned wSclA = ((unsigned)(bLo >> 16) & 0xFFFFu) |
                             (((unsigned)(bHi >> 16) & 0xFu) << 16);
      const unsigned wLocB = ((unsigned)(bLo >> 32) & 0xFFFFu) |
                             (((unsigned)(bHi >> 32) & 0xFu) << 16);
      const unsigned wSclB = ((unsigned)(bLo >> 48) & 0xFFFFu) |
                             (((unsigned)(bHi >> 48) & 0xFu) << 16);

      // ---- two independent scalar chains (SALU fills stall slots) ----
      const int locA = (int)__builtin_ctz(wLocA);
      const int sclA = (int)__builtin_ctz(wSclA);
      int rA = asA - locA; rA += (rA >> 31) & Vn;
      const int invA = (sclA & 1) ? (int)((INVT >> ((sclA >> 1) * 5)) & 31ull) : 0;
      const int oidxA = mod20(invA * rA);

      const int locB = (int)__builtin_ctz(wLocB);
      const int sclB = (int)__builtin_ctz(wSclB);
      int rBt = asB - locB; rBt += (rBt >> 31) & Vn;
      const int invB = (sclB & 1) ? (int)((INVT >> ((sclB >> 1) * 5)) & 31ull) : 0;
      const int oidxB = mod20(invB * rBt);

      // ---- one ds_read_b64 serves both chains (per-lane row select) ----
      if (u != TB - 1) {
        const int om = isB ? oidxB : oidxA;      // v_cndmask
        const float2 e = ew2[om * 32 + pos];     // lanes l,l+32 same bank: free
        nlo += e.x; nhi += e.y;
      }

      // pack oidx (SALU, off-chain): 12 / 12 / 8 per u64
      if (u < 12)      { qA0 |= (unsigned long long)(unsigned)oidxA << (5 * u);
                         qB0 |= (unsigned long long)(unsigned)oidxB << (5 * u); }
      else if (u < 24) { qA1 |= (unsigned long long)(unsigned)oidxA << (5 * (u - 12));
                         qB1 |= (unsigned long long)(unsigned)oidxB << (5 * (u - 12)); }
      else             { qA2 |= (unsigned long long)(unsigned)oidxA << (5 * (u - 24));
                         qB2 |= (unsigned long long)(unsigned)oidxB << (5 * (u - 24)); }
    }

    // ---- batched one-hot writeback: 640 floats per chain, coalesced ----
    {
      const int rl   = lane >> 1;               // step 0..31 of the block
      const int half = lane & 1;                // cols 0-9 or 10-19
      const int sh = 5 * ((rl < 12) ? rl : (rl < 24) ? (rl - 12) : (rl - 24));
      const unsigned long long wA = (rl < 12) ? qA0 : (rl < 24) ? qA1 : qA2;
      const unsigned long long wB = (rl < 12) ? qB0 : (rl < 24) ? qB1 : qB2;
      const int odA = (int)((wA >> sh) & 31ull);
      const int odB = (int)((wB >> sh) & 31ull);
      const int c0 = half * 10;
      float* oa = outA + (size_t)tb * (TB * Vn) + rl * Vn + c0;
      float* ob = outB + (size_t)tb * (TB * Vn) + rl * Vn + c0;
#pragma unroll
      for (int c = 0; c < 10; ++c) oa[c] = (c0 + c == odA) ? 1.0f : 0.0f;
#pragma unroll
      for (int c = 0; c < 10; ++c) ob[c] = (c0 + c == odB) ? 1.0f : 0.0f;
    }

    if (tb != Ln / TB - 1) {
      // ---- deferred exact f32 state walks (same add order as R11) ----
#pragma unroll
      for (int u = 0; u < TB; ++u) {
        const int sh = 5 * ((u < 12) ? u : (u < 24) ? (u - 12) : (u - 24));
        const unsigned long long wA = (u < 12) ? qA0 : (u < 24) ? qA1 : qA2;
        const unsigned long long wB = (u < 12) ? qB0 : (u < 24) ? qB1 : qB2;
        const int ouA = (int)((wA >> sh) & 31ull);
        const int ouB = (int)((wB >> sh) & 31ull);
        sAa += embd[ouA * Dn + lane];
        sAb += embd[ouA * Dn + lane + 64];
        sBa += embd[ouB * Dn + lane];
        sBb += embd[ouB * Dn + lane + 64];
      }
      // ---- Resync pass A (proven R11 numerics) ----
      float tloA, thiA;
      {
        st64[lane]      = (double)sAa;
        st64[lane + 64] = (double)sAb;
        double a0 = 0.0, a1 = 0.0, a2 = 0.0, a3 = 0.0;
        RDOT
        if (own) nets40[jm] = (float)(((a0 + a1) + (a2 + a3)) + bj);
        tloA = nets40[rB * 20 + p];
        thiA = (p < 4) ? nets40[rB * 20 + 16 + p] : -FLT_MAX;
      }
      // ---- Resync pass B ----
      float tloB, thiB;
      {
        st64[lane]      = (double)sBa;
        st64[lane + 64] = (double)sBb;
        double a0 = 0.0, a1 = 0.0, a2 = 0.0, a3 = 0.0;
        RDOT
        if (own) nets40[jm] = (float)(((a0 + a1) + (a2 + a3)) + bj);
        tloB = nets40[rB * 20 + p];
        thiB = (p < 4) ? nets40[rB * 20 + 16 + p] : -FLT_MAX;
      }
      nlo = isB ? tloB : tloA;
      nhi = isB ? thiB : thiA;
    }
  }
}

extern "C" void kernel_launch(void* const* d_in, const int* in_sizes, int n_in,
                              void* d_out, int out_size, void* d_ws, size_t ws_size,
                              hipStream_t stream) {
  const float* x   = (const float*)d_in[0];
  const float* emb = (const float*)d_in[1];
  const float* W   = (const float*)d_in[2];
  const float* b   = (const float*)d_in[3];
  float* out = (float*)d_out;
  hipLaunchKernelGGL(daf_chain, dim3(Bn / CH), dim3(64), 0, stream,
                     x, emb, W, b, out);
}

// Round 13
// 233.327 us; speedup vs baseline: 1.9109x; 1.9109x over previous
//
#include <hip/hip_runtime.h>
#include <cfloat>

// Problem constants (match reference)
constexpr int Bn = 1024, Ln = 1024, Vn = 20, Dn = 128;
constexpr int NJ = 2 * Vn;      // 40 output columns
constexpr int TB = 32;          // steps per block (resync every 2 blocks)

// v mod 20 for 0 <= v <= ~4000 (magic multiply, exact in this range)
__device__ __forceinline__ int mod20(int v) { return v - 20 * ((v * 205) >> 12); }

// ---- DPP helpers (16-lane row reduce, pure VALU) ----
template<int CTRL>
__device__ __forceinline__ float dpp_mov(float v) {
  return __int_as_float(
      __builtin_amdgcn_update_dpp(0, __float_as_int(v), CTRL, 0xF, 0xF, false));
}
template<int CTRL>
__device__ __forceinline__ float dpp_max(float v) {
  return fmaxf(v, dpp_mov<CTRL>(v));
}
__device__ __forceinline__ float max3f(float a, float b, float c) {
  return fmaxf(fmaxf(a, b), c);   // fuses to v_max3_f32
}
// 3-level reduce: pairs via xor1, then max3 over rotations {2,4} and {6,12}.
// Coverage: pairs {b0, b0+2, b0+4} U {b0+6, b0+8, b0+10} U {b0+12, b0+14, b0}
// = all 8 pairs of the 16-lane row, for both parities of p. (ror:N = 0x120+N)
__device__ __forceinline__ float rowmax16(float v) {
  const float a1 = dpp_max<0xB1>(v);                               // pair max
  const float t2 = max3f(a1, dpp_mov<0x122>(a1), dpp_mov<0x124>(a1));
  return max3f(t2, dpp_mov<0x126>(t2), dpp_mov<0x12C>(t2));
}

// inv mod 20 packed table: 5-bit entries for odd s, indexed by s>>1
constexpr unsigned long long INVT =
    (1ull << 0) | (7ull << 5) | (0ull << 10) | (3ull << 15) | (9ull << 20) |
    (11ull << 25) | (17ull << 30) | (0ull << 35) | (13ull << 40) | (19ull << 45);

__global__ __launch_bounds__(64, 1) void daf_chain(
    const float* __restrict__ x, const float* __restrict__ emb,
    const float* __restrict__ W, const float* __restrict__ bvec,
    float* __restrict__ out)
{
  __shared__ float Ws[Dn * NJ];                  // 20480 B: W row-major f32
  __shared__ float embd[Vn * Dn];                // 10240 B: emb rows f32
  __shared__ alignas(8) float ewd2[Vn * 64];     //  5120 B: EW distributed {lo,hi}/pos
  __shared__ alignas(16) double st64[Dn];        //  1024 B: f64 copy of f32 state
  __shared__ float nets40[64];                   //   256 B: resync share (padded)
  __shared__ alignas(16) unsigned char aidx[Ln]; //  1024 B: token index per step

  const int lane = threadIdx.x;
  const int batch = blockIdx.x;
  const int p   = lane & 15;          // position within row
  const int rB  = (lane >> 4) & 1;    // 0 = loc row, 1 = scale row
  const int pos = lane & 31;          // row-pair position (lanes 32..63 mirror)

  // resync column ownership (40 owner lanes)
  const bool own = (lane < Vn) || (lane >= 32 && lane < 32 + Vn);
  const int  jm  = (lane < 32) ? lane : (lane - 32 + Vn);
  const int  jc  = own ? jm : 0;

  // ---- Prologue: stage W, emb; extract token indices (coalesced float4) ----
  // Single-wave block: LDS ops complete in-order within the wave -> no barriers.
  for (int i = lane; i < Dn * NJ; i += 64) Ws[i] = W[i];
  for (int i = lane; i < Vn * Dn; i += 64) embd[i] = emb[i];
  const float4* xb4 = (const float4*)(x + (size_t)batch * Ln * Vn);
  for (int i = lane; i < Ln * (Vn / 4); i += 64) {
    const float4 v = xb4[i];
    const int row = i / 5, cb = (i % 5) * 4;
    if (v.x > 0.5f) aidx[row] = (unsigned char)(cb + 0);
    if (v.y > 0.5f) aidx[row] = (unsigned char)(cb + 1);
    if (v.z > 0.5f) aidx[row] = (unsigned char)(cb + 2);
    if (v.w > 0.5f) aidx[row] = (unsigned char)(cb + 3);
  }

  // ---- EW[k][j] = f64 dot(emb[k], W[:,j]) -> f32, distributed layout (R7) ----
  for (int e = lane; e < Vn * NJ; e += 64) {
    const int k = e / NJ, j = e - k * NJ;
    double acc = 0.0;
#pragma unroll 4
    for (int d = 0; d < Dn; ++d)
      acc = __builtin_fma((double)embd[k * Dn + d], (double)Ws[d * NJ + j], acc);
    int q, slot;
    if (j < 16)      { q = j;             slot = 0; }
    else if (j < 20) { q = j - 16;        slot = 1; }
    else if (j < 36) { q = 16 + (j - 20); slot = 0; }
    else             { q = 16 + (j - 36); slot = 1; }
    ewd2[k * 64 + q * 2 + slot] = (float)acc;
  }
  if ((pos & 15) >= 4)   // zero undefined hi slots so (-FLT_MAX += 0) stays put
    for (int k = 0; k < Vn; ++k) ewd2[k * 64 + pos * 2 + 1] = 0.0f;

  // ---- init nets (distributed): exact f32 b (state 0) ----
  const int jlo = rB ? (20 + p) : p;
  float nlo = bvec[jlo];
  float nhi = (p < 4) ? bvec[jlo + 16] : -FLT_MAX;
  const double bj = (double)bvec[jc];

  float s32a = 0.0f, s32b = 0.0f;   // bit-exact f32 state walk (d=lane, lane+64)
  float* outb = out + (size_t)batch * Ln * Vn;
  const double2* st2 = (const double2*)st64;
  const float*   Wsc = Ws + jc;
  const float2*  ew2 = (const float2*)ewd2;

  for (int tb = 0; tb < Ln / TB; ++tb) {
    // token prefetch: 32 tokens -> 8 SGPRs (two broadcast b128 reads)
    const uint4 tva = *(const uint4*)(aidx + tb * TB);
    const uint4 tvb = *(const uint4*)(aidx + tb * TB + 16);
    const int tk0 = __builtin_amdgcn_readfirstlane((int)tva.x);
    const int tk1 = __builtin_amdgcn_readfirstlane((int)tva.y);
    const int tk2 = __builtin_amdgcn_readfirstlane((int)tva.z);
    const int tk3 = __builtin_amdgcn_readfirstlane((int)tva.w);
    const int tk4 = __builtin_amdgcn_readfirstlane((int)tvb.x);
    const int tk5 = __builtin_amdgcn_readfirstlane((int)tvb.y);
    const int tk6 = __builtin_amdgcn_readfirstlane((int)tvb.z);
    const int tk7 = __builtin_amdgcn_readfirstlane((int)tvb.w);

    unsigned long long q0 = 0ull, q1 = 0ull, q2 = 0ull;  // 32 x 5-bit oidx

#pragma unroll
    for (int u = 0; u < TB; ++u) {
      const int tw = (u < 4) ? tk0 : (u < 8) ? tk1 : (u < 12) ? tk2 :
                     (u < 16) ? tk3 : (u < 20) ? tk4 : (u < 24) ? tk5 :
                     (u < 28) ? tk6 : tk7;
      const int as = (tw >> ((u & 3) * 8)) & 0xFF;   // SALU extract

      // ---- argmax: 3-level max3/ror reduce; ballot index extraction ----
      float m = fmaxf(nlo, nhi);
      m = rowmax16(m);
      const unsigned long long bLo = __ballot(nlo == m);
      const unsigned long long bHi = __ballot(nhi == m);
      const unsigned wLoc = ((unsigned)bLo & 0xFFFFu) | (((unsigned)bHi & 0xFu) << 16);
      const unsigned wScl = ((unsigned)(bLo >> 16) & 0xFFFFu) |
                            (((unsigned)(bHi >> 16) & 0xFu) << 16);
      const int locI = (int)__builtin_ctz(wLoc);   // first-max = smallest j
      const int sclI = (int)__builtin_ctz(wScl);

      // oidx = (inv20(scale) * ((a + 20 - loc))) mod 20  (scalar chain)
      const int r = as + Vn - locI;                // in [1, 39]
      const int inv = (sclI & 1) ? (int)((INVT >> ((sclI >> 1) * 5)) & 31ull) : 0;
      const int oidx = mod20(inv * r);             // inv*r <= 741, magic exact

      // EW fetch + net update first (the serial chain); bookkeeping after.
      if (u != TB - 1) {
        const float2 e = ew2[oidx * 32 + pos];     // one ds_read_b64, sole LDS op
        nlo += e.x; nhi += e.y;
      }

      // pack oidx (SALU, off-chain): 12 / 12 / 8 per u64
      if (u < 12)      q0 |= (unsigned long long)(unsigned)oidx << (5 * u);
      else if (u < 24) q1 |= (unsigned long long)(unsigned)oidx << (5 * (u - 12));
      else             q2 |= (unsigned long long)(unsigned)oidx << (5 * (u - 24));
    }

    // ---- batched one-hot writeback: 640 floats, coalesced (10/lane) ----
    {
      const int rl   = lane >> 1;               // step 0..31 of the block
      const int half = lane & 1;                // cols 0-9 or 10-19
      const unsigned long long w = (rl < 12) ? q0 : (rl < 24) ? q1 : q2;
      const int sh = 5 * ((rl < 12) ? rl : (rl < 24) ? (rl - 12) : (rl - 24));
      const int od = (int)((w >> sh) & 31ull);
      float* ob = outb + (size_t)tb * (TB * Vn) + rl * Vn + half * 10;
      const int c0 = half * 10;
#pragma unroll
      for (int c = 0; c < 10; ++c)
        ob[c] = (c0 + c == od) ? 1.0f : 0.0f;
    }

    if (tb != Ln / TB - 1) {
      // ---- deferred exact f32 state walk: same order/values as per-step ----
#pragma unroll
      for (int u = 0; u < TB; ++u) {
        const unsigned long long w = (u < 12) ? q0 : (u < 24) ? q1 : q2;
        const int sh = 5 * ((u < 12) ? u : (u < 24) ? (u - 12) : (u - 24));
        const int ou = (int)((w >> sh) & 31ull);
        s32a += embd[ou * Dn + lane];
        s32b += embd[ou * Dn + lane + 64];
      }
      // ---- Resync every OTHER block (window 64): proven R9 numerics ----
      if (tb & 1) {
        st64[lane]      = (double)s32a;
        st64[lane + 64] = (double)s32b;
        double a0 = 0.0, a1 = 0.0, a2 = 0.0, a3 = 0.0;
#pragma unroll
        for (int d = 0; d < Dn; d += 4) {
          const double2 sA = st2[d >> 1];
          const double2 sB = st2[(d >> 1) + 1];
          a0 = __builtin_fma(sA.x, (double)Wsc[(d + 0) * NJ], a0);
          a1 = __builtin_fma(sA.y, (double)Wsc[(d + 1) * NJ], a1);
          a2 = __builtin_fma(sB.x, (double)Wsc[(d + 2) * NJ], a2);
          a3 = __builtin_fma(sB.y, (double)Wsc[(d + 3) * NJ], a3);
        }
        if (own) nets40[jm] = (float)(((a0 + a1) + (a2 + a3)) + bj);
        nlo = nets40[rB * 20 + p];
        nhi = (p < 4) ? nets40[rB * 20 + 16 + p] : -FLT_MAX;
      }
    }
  }
}

extern "C" void kernel_launch(void* const* d_in, const int* in_sizes, int n_in,
                              void* d_out, int out_size, void* d_ws, size_t ws_size,
                              hipStream_t stream) {
  const float* x   = (const float*)d_in[0];
  const float* emb = (const float*)d_in[1];
  const float* W   = (const float*)d_in[2];
  const float* b   = (const float*)d_in[3];
  float* out = (float*)d_out;
  hipLaunchKernelGGL(daf_chain, dim3(Bn), dim3(64), 0, stream,
                     x, emb, W, b, out);
}